// Round 5
// baseline (357.503 us; speedup 1.0000x reference)
//
#include <hip/hip_runtime.h>
#include <hip/hip_bf16.h>
#include <hip/hip_fp16.h>
#include <math.h>
#include <stdint.h>

// ---------------- tunables ----------------
constexpr int TPB         = 256;      // threads per block
constexpr int NODES_PER_B = 256;      // nodes per bucket (bin = node >> 8)
constexpr int NBLK        = 1024;     // phase-1 blocks (power of 2)
constexpr int C_SLOT      = 32;       // record slots per (bucket, block) group (λ≈16, +4σ)
constexpr int SPLIT       = 4;        // phase-2 blocks per bucket
constexpr int MAX_NB      = 512;      // max buckets (LDS cursor array)
constexpr int OCAP        = 1000000;  // overflow list capacity

// Record: 8 B = { u8 local_node, 3 × fp16 force (sign pre-applied) }
__device__ __forceinline__ uint64_t pack_rec(int local, float fx, float fy, float fz) {
    uint64_t hx = __half_as_ushort(__float2half(fx));
    uint64_t hy = __half_as_ushort(__float2half(fy));
    uint64_t hz = __half_as_ushort(__float2half(fz));
    return (uint64_t)(unsigned)local | (hx << 16) | (hy << 32) | (hz << 48);
}

// ---------------- phase 1: force + bucket scatter ----------------
__global__ void __launch_bounds__(TPB)
p1_force_bucket(const float* __restrict__ disp,
                const float* __restrict__ a,
                const float* __restrict__ b,
                const int* __restrict__ src,
                const int* __restrict__ dst,
                uint64_t* __restrict__ records,  // [NB][NBLK][C_SLOT]
                int* __restrict__ counts,        // [NB][NBLK]
                uint4* __restrict__ ovf,
                int* __restrict__ ovf_cnt,
                int E, int NB, int epb) {
    __shared__ int cursor[MAX_NB];
    int t = threadIdx.x;
    for (int i = t; i < NB; i += TPB) cursor[i] = 0;
    __syncthreads();

    int blk = blockIdx.x;
    int base = blk * epb;
    int end = min(base + epb, E);

    for (int e = base + t; e < end; e += TPB) {
        float dx = disp[3 * e + 0];
        float dy = disp[3 * e + 1];
        float dz = disp[3 * e + 2];
        float r2 = dx * dx + dy * dy + dz * dz;
        // force = -dE/ddisp = -2*disp*(a - b*exp(-r2))
        float coef = -2.0f * (a[e] - b[e] * __expf(-r2));
        float fx = coef * dx, fy = coef * dy, fz = coef * dz;

        int nodes[2] = { src[e], dst[e] };
        float sgn[2] = { 1.0f, -1.0f };
#pragma unroll
        for (int j = 0; j < 2; ++j) {
            int node = nodes[j];
            int bin = node >> 8;
            int local = node & (NODES_PER_B - 1);
            float gx = sgn[j] * fx, gy = sgn[j] * fy, gz = sgn[j] * fz;
            int r = atomicAdd(&cursor[bin], 1);   // LDS ds_add_rtn_u32
            if (r < C_SLOT) {
                // shift-friendly: ((bin*NBLK + blk)*C_SLOT + r)
                size_t off = (((size_t)bin << 10) + blk) * C_SLOT + r;
                records[off] = pack_rec(local, gx, gy, gz);
            } else {
                int o = atomicAdd(ovf_cnt, 1);    // rare (~1e2 total)
                if (o < OCAP) {
                    uint4 rec;
                    rec.x = (unsigned)node;
                    rec.y = __float_as_uint(gx);
                    rec.z = __float_as_uint(gy);
                    rec.w = __float_as_uint(gz);
                    ovf[o] = rec;
                }
            }
        }
    }
    __syncthreads();
    for (int i = t; i < NB; i += TPB)
        counts[((size_t)i << 10) + blk] = min(cursor[i], C_SLOT);
}

// ---------------- phase 2: per-(bucket, part) LDS reduce -> partials ----------------
__global__ void __launch_bounds__(TPB)
p2_bucket_reduce(const uint64_t* __restrict__ records,
                 const int* __restrict__ counts,
                 float* __restrict__ partials,   // [SPLIT][NB*768]
                 int NB) {
    constexpr int GPP = NBLK / SPLIT;            // 256 groups per part
    __shared__ float accum[NODES_PER_B * 3];
    __shared__ int cnt[GPP];
    int t = threadIdx.x;
    int bucket = blockIdx.x >> 2;                // SPLIT = 4
    int part = blockIdx.x & (SPLIT - 1);

    for (int i = t; i < NODES_PER_B * 3; i += TPB) accum[i] = 0.0f;
    for (int i = t; i < GPP; i += TPB)
        cnt[i] = counts[((size_t)bucket << 10) + part * GPP + i];
    __syncthreads();

    const uint64_t* rbase =
        records + (((size_t)bucket << 10) + (size_t)part * GPP) * C_SLOT;
    constexpr int SLOTS = GPP * C_SLOT;          // 8192
    for (int s = t; s < SLOTS; s += TPB) {
        int g = s >> 5;                          // C_SLOT = 32
        int idx = s & (C_SLOT - 1);
        if (idx < cnt[g]) {
            uint64_t rec = rbase[s];
            int local = (int)(rec & 0xff);
            float fx = __half2float(__ushort_as_half((unsigned short)(rec >> 16)));
            float fy = __half2float(__ushort_as_half((unsigned short)(rec >> 32)));
            float fz = __half2float(__ushort_as_half((unsigned short)(rec >> 48)));
            atomicAdd(&accum[local * 3 + 0], fx);   // ds_add_f32
            atomicAdd(&accum[local * 3 + 1], fy);
            atomicAdd(&accum[local * 3 + 2], fz);
        }
    }
    __syncthreads();

    float* pbase = partials + (size_t)part * ((size_t)NB * NODES_PER_B * 3)
                 + (size_t)bucket * NODES_PER_B * 3;
    for (int i = t; i < NODES_PER_B * 3; i += TPB) pbase[i] = accum[i];
}

// ---------------- phase 4: sum the SPLIT partials -> out ----------------
__global__ void __launch_bounds__(TPB)
p4_sum_partials(const float* __restrict__ partials, float* __restrict__ out,
                int out_size, size_t pstride) {
    int i = blockIdx.x * blockDim.x + threadIdx.x;
    if (i >= out_size) return;
    float acc = 0.0f;
#pragma unroll
    for (int p = 0; p < SPLIT; ++p)
        acc += partials[(size_t)p * pstride + i];
    out[i] = acc;
}

// ---------------- phase 3: apply rare overflow records (after p4) ----------------
__global__ void __launch_bounds__(TPB)
p3_overflow(const uint4* __restrict__ ovf, const int* __restrict__ ovf_cnt,
            float* __restrict__ out) {
    int n = *ovf_cnt;
    if (n > OCAP) n = OCAP;
    int stride = gridDim.x * blockDim.x;
    for (int i = blockIdx.x * blockDim.x + threadIdx.x; i < n; i += stride) {
        uint4 rec = ovf[i];
        int node = (int)rec.x;
        unsafeAtomicAdd(&out[node * 3 + 0], __uint_as_float(rec.y));
        unsafeAtomicAdd(&out[node * 3 + 1], __uint_as_float(rec.z));
        unsafeAtomicAdd(&out[node * 3 + 2], __uint_as_float(rec.w));
    }
}

// ---------------- fallback: direct atomic scatter ----------------
__global__ void __launch_bounds__(TPB)
edge_force_scatter_direct(const float* __restrict__ disp,
                          const float* __restrict__ a,
                          const float* __restrict__ b,
                          const int* __restrict__ src,
                          const int* __restrict__ dst,
                          float* __restrict__ out,
                          int E) {
    int e = blockIdx.x * blockDim.x + threadIdx.x;
    if (e >= E) return;
    float dx = disp[3 * e + 0], dy = disp[3 * e + 1], dz = disp[3 * e + 2];
    float r2 = dx * dx + dy * dy + dz * dz;
    float coef = -2.0f * (a[e] - b[e] * __expf(-r2));
    float fx = coef * dx, fy = coef * dy, fz = coef * dz;
    int s = 3 * src[e], d = 3 * dst[e];
    unsafeAtomicAdd(&out[s + 0], fx);
    unsafeAtomicAdd(&out[s + 1], fy);
    unsafeAtomicAdd(&out[s + 2], fz);
    unsafeAtomicAdd(&out[d + 0], -fx);
    unsafeAtomicAdd(&out[d + 1], -fy);
    unsafeAtomicAdd(&out[d + 2], -fz);
}

extern "C" void kernel_launch(void* const* d_in, const int* in_sizes, int n_in,
                              void* d_out, int out_size, void* d_ws, size_t ws_size,
                              hipStream_t stream) {
    const float* disp = (const float*)d_in[0];   // [E,3]
    const float* a    = (const float*)d_in[1];   // [E]
    const float* b    = (const float*)d_in[2];   // [E]
    const int*   ei   = (const int*)d_in[3];     // [2,E]

    int E = in_sizes[1];
    int N = in_sizes[4];
    float* out = (float*)d_out;

    int NB = (N + NODES_PER_B - 1) / NODES_PER_B;
    int epb = (E + NBLK - 1) / NBLK;
    size_t pstride = (size_t)NB * NODES_PER_B * 3;

    size_t rec_slots = (size_t)NB * NBLK * C_SLOT;
    size_t need = rec_slots * sizeof(uint64_t)
                + (size_t)OCAP * sizeof(uint4)
                + (size_t)NB * NBLK * sizeof(int)
                + (size_t)SPLIT * pstride * sizeof(float)
                + 64;

    if (NB <= MAX_NB && ws_size >= need) {
        uint64_t* records = (uint64_t*)d_ws;
        uint4*    ovf     = (uint4*)(records + rec_slots);
        int*      counts  = (int*)(ovf + OCAP);
        float*    partials= (float*)(counts + (size_t)NB * NBLK);
        int*      ovf_cnt = (int*)(partials + (size_t)SPLIT * pstride);

        hipMemsetAsync(ovf_cnt, 0, sizeof(int), stream);

        p1_force_bucket<<<NBLK, TPB, 0, stream>>>(
            disp, a, b, ei, ei + E, records, counts, ovf, ovf_cnt, E, NB, epb);
        p2_bucket_reduce<<<NB * SPLIT, TPB, 0, stream>>>(
            records, counts, partials, NB);
        int grid4 = (out_size + TPB - 1) / TPB;
        p4_sum_partials<<<grid4, TPB, 0, stream>>>(partials, out, out_size, pstride);
        p3_overflow<<<64, TPB, 0, stream>>>(ovf, ovf_cnt, out);
    } else {
        hipMemsetAsync(d_out, 0, (size_t)out_size * sizeof(float), stream);
        int grid = (E + TPB - 1) / TPB;
        edge_force_scatter_direct<<<grid, TPB, 0, stream>>>(
            disp, a, b, ei, ei + E, out, E);
    }
}